// Round 11
// baseline (50.411 us; speedup 1.0000x reference)
//
#include <hip/hip_runtime.h>

#define NN 4096
#define EE 65536
#define DD 128
#define NPB 8               // nodes per block
#define NB (NN / NPB)       // 512 blocks -> 2+ blocks/CU co-resident

// acc[i] (2 adjacent cols) += y[ng*4+i] @ W over this thread's K-slice.
// Wave = 64 lanes x 2 cols = all 128 cols -> y-address wave-uniform (LDS
// broadcast); one float2 W load feeds 8 FMAs (4 nodes x 2 cols).
__device__ __forceinline__ void gemm24(const float* __restrict__ W, int kstart,
                                       int nk4, int c2, const float* __restrict__ y,
                                       int ystr, float2 acc[4]) {
#pragma unroll 4
    for (int k4 = 0; k4 < nk4; ++k4) {
        int k = kstart + k4 * 4;
        float4 yv[4];
#pragma unroll
        for (int i = 0; i < 4; ++i)
            yv[i] = *(const float4*)&y[i * ystr + k];   // LDS broadcast, uniform addr
#pragma unroll
        for (int kk = 0; kk < 4; ++kk) {
            float2 w = *(const float2*)&W[(size_t)(k + kk) * DD + c2];  // L1/L2
#pragma unroll
            for (int i = 0; i < 4; ++i) {
                float e = kk == 0 ? yv[i].x : kk == 1 ? yv[i].y
                        : kk == 2 ? yv[i].z : yv[i].w;
                acc[i].x += e * w.x;
                acc[i].y += e * w.y;
            }
        }
    }
}

// Single kernel: in-block degree scan + fused h0 -> layer0 -> layer1 -> out.
// Attention output is exactly zero (multiplicative -1e6 mask => softmax max is a
// huge positive cross-graph logit => within-graph exp underflows to 0; the zero
// mask then kills the cross-graph cols), so only xp=h+bo and the LN2/FF path survive.
// 512 blocks x 512 thr, 8 nodes/block -> 2-4 blocks/CU overlap barriers/scans.
// GEMM thread = (c2=2*(tid&63), ng=(tid>>6)&1 [4 nodes], ks=tid>>7 [K-quarter]);
// wave-per-node phases: wave n handles node n, lane j -> cols j, j+64.
__global__ __launch_bounds__(512) void k_one(
    const float* __restrict__ x, const int* __restrict__ ei,
    const float* __restrict__ W_in, const float* __restrict__ b_in,
    const float* __restrict__ z_in, const float* __restrict__ z_out,
    const float* __restrict__ bo_all, const float* __restrict__ g_all,
    const float* __restrict__ b_all, const float* __restrict__ Wff_all,
    const float* __restrict__ bff_all, const float* __restrict__ W_out,
    const float* __restrict__ b_out, float* __restrict__ out) {
    __shared__ float part[4][NPB][DD];  // 16KB K-split partials
    __shared__ float ybuf[NPB][DD];     // 4KB  GEMM input (LN out / h)
    __shared__ float xps[NPB][DD];      // 4KB  residual stash
    __shared__ float xs[NPB][64];       // 2KB  staged x rows
    __shared__ int cin[NPB], cout_[NPB];
    const int tid = threadIdx.x;
    const int n0 = blockIdx.x * NPB;
    const int lane = tid & 63;
    const int c2 = lane * 2;            // adjacent col pair
    const int ng = (tid >> 6) & 1;      // node group of 4
    const int ks = tid >> 7;            // K-slice 0..3
    const int wn = tid >> 6;            // wave = node (0..7) for fused phases
    const int j = lane;

    // ---- stage x rows + zero LDS degree counters ----
    xs[wn][j] = x[(size_t)(n0 + wn) * 64 + j];
    if (tid < NPB) { cin[tid] = 0; cout_[tid] = 0; }
    __syncthreads();

    // ---- degree scan (this block's 8 nodes over all edges; L2-resident) ----
    {
        const int4* s4 = (const int4*)ei;
        const int4* d4 = (const int4*)(ei + EE);
#pragma unroll 4
        for (int i = tid; i < EE / 4; i += 512) {
            int4 s = s4[i];
            if ((unsigned)(s.x - n0) < (unsigned)NPB) atomicAdd(&cout_[s.x - n0], 1);
            if ((unsigned)(s.y - n0) < (unsigned)NPB) atomicAdd(&cout_[s.y - n0], 1);
            if ((unsigned)(s.z - n0) < (unsigned)NPB) atomicAdd(&cout_[s.z - n0], 1);
            if ((unsigned)(s.w - n0) < (unsigned)NPB) atomicAdd(&cout_[s.w - n0], 1);
            int4 d = d4[i];
            if ((unsigned)(d.x - n0) < (unsigned)NPB) atomicAdd(&cin[d.x - n0], 1);
            if ((unsigned)(d.y - n0) < (unsigned)NPB) atomicAdd(&cin[d.y - n0], 1);
            if ((unsigned)(d.z - n0) < (unsigned)NPB) atomicAdd(&cin[d.z - n0], 1);
            if ((unsigned)(d.w - n0) < (unsigned)NPB) atomicAdd(&cin[d.w - n0], 1);
        }
    }

    float2 acc[4];

    // ---- h0 GEMM (K=64, slice=16) ----
#pragma unroll
    for (int i = 0; i < 4; ++i) acc[i] = make_float2(0.f, 0.f);
    gemm24(W_in, ks * 16, 4, c2, &xs[ng * 4][0], 64, acc);
#pragma unroll
    for (int i = 0; i < 4; ++i) *(float2*)&part[ks][ng * 4 + i][c2] = acc[i];
    __syncthreads();

    // ---- fused: h0-reduce + centrality + LN(layer0) ----
    {
        float vA = part[0][wn][j] + part[1][wn][j] + part[2][wn][j] + part[3][wn][j];
        float vB = part[0][wn][j + 64] + part[1][wn][j + 64]
                 + part[2][wn][j + 64] + part[3][wn][j + 64];
        int di = min(cin[wn], 63), dq = min(cout_[wn], 63);
        float hA = vA + b_in[j] + z_in[(size_t)di * DD + j] + z_out[(size_t)dq * DD + j];
        float hB = vB + b_in[j + 64] + z_in[(size_t)di * DD + j + 64]
                 + z_out[(size_t)dq * DD + j + 64];
        float xpA = hA + bo_all[j], xpB = hB + bo_all[j + 64];
        float s = xpA + xpB;
        s += __shfl_xor(s, 32); s += __shfl_xor(s, 16); s += __shfl_xor(s, 8);
        s += __shfl_xor(s, 4);  s += __shfl_xor(s, 2);  s += __shfl_xor(s, 1);
        float mu = s * (1.f / 128.f);
        float cA = xpA - mu, cB = xpB - mu;
        float v = cA * cA + cB * cB;
        v += __shfl_xor(v, 32); v += __shfl_xor(v, 16); v += __shfl_xor(v, 8);
        v += __shfl_xor(v, 4);  v += __shfl_xor(v, 2);  v += __shfl_xor(v, 1);
        float r = rsqrtf(v * (1.f / 128.f) + 1e-5f);
        ybuf[wn][j] = cA * r * g_all[j] + b_all[j];
        ybuf[wn][j + 64] = cB * r * g_all[j + 64] + b_all[j + 64];
        xps[wn][j] = xpA;
        xps[wn][j + 64] = xpB;
    }
    __syncthreads();

    // ---- FF0 GEMM (K=128, slice=32) ----
#pragma unroll
    for (int i = 0; i < 4; ++i) acc[i] = make_float2(0.f, 0.f);
    gemm24(Wff_all, ks * 32, 8, c2, &ybuf[ng * 4][0], DD, acc);
#pragma unroll
    for (int i = 0; i < 4; ++i) *(float2*)&part[ks][ng * 4 + i][c2] = acc[i];
    __syncthreads();

    // ---- fused: FF0-reduce + residual + LN(layer1) ----
    {
        float vA = part[0][wn][j] + part[1][wn][j] + part[2][wn][j] + part[3][wn][j];
        float vB = part[0][wn][j + 64] + part[1][wn][j + 64]
                 + part[2][wn][j + 64] + part[3][wn][j + 64];
        float hA = vA + bff_all[j] + xps[wn][j];
        float hB = vB + bff_all[j + 64] + xps[wn][j + 64];
        float xpA = hA + bo_all[DD + j], xpB = hB + bo_all[DD + j + 64];
        float s = xpA + xpB;
        s += __shfl_xor(s, 32); s += __shfl_xor(s, 16); s += __shfl_xor(s, 8);
        s += __shfl_xor(s, 4);  s += __shfl_xor(s, 2);  s += __shfl_xor(s, 1);
        float mu = s * (1.f / 128.f);
        float cA = xpA - mu, cB = xpB - mu;
        float v = cA * cA + cB * cB;
        v += __shfl_xor(v, 32); v += __shfl_xor(v, 16); v += __shfl_xor(v, 8);
        v += __shfl_xor(v, 4);  v += __shfl_xor(v, 2);  v += __shfl_xor(v, 1);
        float r = rsqrtf(v * (1.f / 128.f) + 1e-5f);
        ybuf[wn][j] = cA * r * g_all[DD + j] + b_all[DD + j];
        ybuf[wn][j + 64] = cB * r * g_all[DD + j + 64] + b_all[DD + j + 64];
        xps[wn][j] = xpA;
        xps[wn][j + 64] = xpB;
    }
    __syncthreads();

    // ---- FF1 GEMM ----
#pragma unroll
    for (int i = 0; i < 4; ++i) acc[i] = make_float2(0.f, 0.f);
    gemm24(Wff_all + DD * DD, ks * 32, 8, c2, &ybuf[ng * 4][0], DD, acc);
#pragma unroll
    for (int i = 0; i < 4; ++i) *(float2*)&part[ks][ng * 4 + i][c2] = acc[i];
    __syncthreads();

    // ---- fused: FF1-reduce + residual -> h (into ybuf for out-GEMM) ----
    {
        float vA = part[0][wn][j] + part[1][wn][j] + part[2][wn][j] + part[3][wn][j];
        float vB = part[0][wn][j + 64] + part[1][wn][j + 64]
                 + part[2][wn][j + 64] + part[3][wn][j + 64];
        ybuf[wn][j] = vA + bff_all[DD + j] + xps[wn][j];
        ybuf[wn][j + 64] = vB + bff_all[DD + j + 64] + xps[wn][j + 64];
    }
    __syncthreads();

    // ---- out GEMM ----
#pragma unroll
    for (int i = 0; i < 4; ++i) acc[i] = make_float2(0.f, 0.f);
    gemm24(W_out, ks * 32, 8, c2, &ybuf[ng * 4][0], DD, acc);
#pragma unroll
    for (int i = 0; i < 4; ++i) *(float2*)&part[ks][ng * 4 + i][c2] = acc[i];
    __syncthreads();

    // ---- final reduce + b_out + store (coalesced) ----
    {
        float vA = part[0][wn][j] + part[1][wn][j] + part[2][wn][j] + part[3][wn][j];
        float vB = part[0][wn][j + 64] + part[1][wn][j + 64]
                 + part[2][wn][j + 64] + part[3][wn][j + 64];
        out[(size_t)(n0 + wn) * DD + j] = vA + b_out[j];
        out[(size_t)(n0 + wn) * DD + j + 64] = vB + b_out[j + 64];
    }
}

extern "C" void kernel_launch(void* const* d_in, const int* in_sizes, int n_in,
                              void* d_out, int out_size, void* d_ws, size_t ws_size,
                              hipStream_t stream) {
    // inputs: 0 x, 1 edge_index, 2 ptr, 3 dist, 4 W_in, 5 b_in, 6 z_in, 7 z_out,
    // 8 b_spat, 9 Wq, 10 bq, 11 Wk, 12 bk, 13 Wv, 14 bv, 15 Wo, 16 bo,
    // 17 ln1_g, 18 ln1_b, 19 ln2_g, 20 ln2_b, 21 Wff, 22 bff, 23 W_out, 24 b_out
    const float* x = (const float*)d_in[0];
    const int* ei = (const int*)d_in[1];
    const float* W_in = (const float*)d_in[4];
    const float* b_in = (const float*)d_in[5];
    const float* z_in = (const float*)d_in[6];
    const float* z_out = (const float*)d_in[7];
    const float* bo = (const float*)d_in[16];
    const float* ln2_g = (const float*)d_in[19];
    const float* ln2_b = (const float*)d_in[20];
    const float* Wff = (const float*)d_in[21];
    const float* bff = (const float*)d_in[22];
    const float* W_out = (const float*)d_in[23];
    const float* b_out = (const float*)d_in[24];
    float* out = (float*)d_out;

    k_one<<<NB, 512, 0, stream>>>(x, ei, W_in, b_in, z_in, z_out,
                                  bo, ln2_g, ln2_b, Wff, bff, W_out, b_out, out);
}

// Round 12
// 37.291 us; speedup vs baseline: 1.3518x; 1.3518x over previous
//
#include <hip/hip_runtime.h>

#define NN 4096
#define EE 65536
#define DD 128

// FF/out GEMM: acc[i] (2 adjacent cols) += y[ng*4+i] @ W over K-slice.
// Wave covers all 128 cols -> y-address wave-uniform (LDS broadcast);
// one float2 W load feeds 8 FMAs (4 nodes x 2 cols).
__device__ __forceinline__ void gemm24(const float* __restrict__ W, int kstart,
                                       int nk4, int c2, const float* __restrict__ y,
                                       float2 acc[4]) {
#pragma unroll 4
    for (int k4 = 0; k4 < nk4; ++k4) {
        int k = kstart + k4 * 4;
        float4 yv[4];
#pragma unroll
        for (int i = 0; i < 4; ++i)
            yv[i] = *(const float4*)&y[i * DD + k];
#pragma unroll
        for (int kk = 0; kk < 4; ++kk) {
            float2 w = *(const float2*)&W[(size_t)(k + kk) * DD + c2];
#pragma unroll
            for (int i = 0; i < 4; ++i) {
                float e = kk == 0 ? yv[i].x : kk == 1 ? yv[i].y
                        : kk == 2 ? yv[i].z : yv[i].w;
                acc[i].x += e * w.x;
                acc[i].y += e * w.y;
            }
        }
    }
}

// Single kernel. Attention output is exactly zero (multiplicative -1e6 mask =>
// softmax max is a huge positive cross-graph logit => within-graph exp underflows
// to 0; the zero mask then kills the cross-graph cols), so only xp=h+bo and the
// LN2/FF path survive. 256 blocks x 1024 thr (1 block/CU).
// Phase A (wave-role split): waves 0-7 h0-GEMM (x read from global, wave-uniform
// broadcast); waves 8-15 edge-scan into per-wave LDS counters. Then 16-wave
// phases: fused reduce+LN, FF0, FF1, out (4-way split-K via part[]).
__global__ __launch_bounds__(1024) void k_one(
    const float* __restrict__ x, const int* __restrict__ ei,
    const float* __restrict__ W_in, const float* __restrict__ b_in,
    const float* __restrict__ z_in, const float* __restrict__ z_out,
    const float* __restrict__ bo_all, const float* __restrict__ g_all,
    const float* __restrict__ b_all, const float* __restrict__ Wff_all,
    const float* __restrict__ bff_all, const float* __restrict__ W_out,
    const float* __restrict__ b_out, float* __restrict__ out) {
    __shared__ float part[4][16][DD];   // 32KB K-split partials
    __shared__ float ybuf[16][DD];      // 8KB  GEMM input (LN out / h)
    __shared__ float xps[16][DD];       // 8KB  residual stash
    __shared__ int cinW[8][16];         // per-scan-wave degree counters
    __shared__ int coutW[8][16];
    const int tid = threadIdx.x;
    const int n0 = blockIdx.x * 16;
    const int lane = tid & 63;
    const int c2 = lane * 2;
    const int wn = tid >> 6;            // wave id / node for per-node phases
    const int j = lane;

    if (wn < 8) {
        // ---- waves 0-7: h0 GEMM (K=64, 2-way split; x from global) ----
        const int ng = (tid >> 6) & 3;          // node group of 4
        const int ks = (tid >> 8) & 1;          // K-half
        const float* xrow = x + (size_t)(n0 + ng * 4) * 64 + ks * 32;
        float2 acc[4] = {{0.f,0.f},{0.f,0.f},{0.f,0.f},{0.f,0.f}};
#pragma unroll
        for (int k4 = 0; k4 < 8; ++k4) {
            int k = k4 * 4;
            float4 yv[4];
#pragma unroll
            for (int i = 0; i < 4; ++i)
                yv[i] = *(const float4*)&xrow[i * 64 + k];   // wave-uniform bcast
#pragma unroll
            for (int kk = 0; kk < 4; ++kk) {
                float2 w = *(const float2*)&W_in[(size_t)(ks * 32 + k + kk) * DD + c2];
#pragma unroll
                for (int i = 0; i < 4; ++i) {
                    float e = kk == 0 ? yv[i].x : kk == 1 ? yv[i].y
                            : kk == 2 ? yv[i].z : yv[i].w;
                    acc[i].x += e * w.x;
                    acc[i].y += e * w.y;
                }
            }
        }
#pragma unroll
        for (int i = 0; i < 4; ++i) *(float2*)&part[ks][ng * 4 + i][c2] = acc[i];
    } else {
        // ---- waves 8-15: degree scan into this wave's private counters ----
        const int sw = wn - 8;
        if (lane < 16) { cinW[sw][lane] = 0; coutW[sw][lane] = 0; }
        asm volatile("s_waitcnt lgkmcnt(0)" ::: "memory");   // same-wave init order
        const int4* s4 = (const int4*)ei;
        const int4* d4 = (const int4*)(ei + EE);
        const int t = tid - 512;
#pragma unroll 4
        for (int i = t; i < EE / 4; i += 512) {
            int4 s = s4[i];
            if ((unsigned)(s.x - n0) < 16u) atomicAdd(&coutW[sw][s.x - n0], 1);
            if ((unsigned)(s.y - n0) < 16u) atomicAdd(&coutW[sw][s.y - n0], 1);
            if ((unsigned)(s.z - n0) < 16u) atomicAdd(&coutW[sw][s.z - n0], 1);
            if ((unsigned)(s.w - n0) < 16u) atomicAdd(&coutW[sw][s.w - n0], 1);
            int4 d = d4[i];
            if ((unsigned)(d.x - n0) < 16u) atomicAdd(&cinW[sw][d.x - n0], 1);
            if ((unsigned)(d.y - n0) < 16u) atomicAdd(&cinW[sw][d.y - n0], 1);
            if ((unsigned)(d.z - n0) < 16u) atomicAdd(&cinW[sw][d.z - n0], 1);
            if ((unsigned)(d.w - n0) < 16u) atomicAdd(&cinW[sw][d.w - n0], 1);
        }
    }
    __syncthreads();

    // ---- fused: h0-reduce + centrality + LN(layer0)  (wave wn = node wn) ----
    {
        float vA = part[0][wn][j] + part[1][wn][j];
        float vB = part[0][wn][j + 64] + part[1][wn][j + 64];
        int din = 0, dout = 0;
#pragma unroll
        for (int w = 0; w < 8; ++w) { din += cinW[w][wn]; dout += coutW[w][wn]; }
        int di = min(din, 63), dq = min(dout, 63);
        float hA = vA + b_in[j] + z_in[(size_t)di * DD + j] + z_out[(size_t)dq * DD + j];
        float hB = vB + b_in[j + 64] + z_in[(size_t)di * DD + j + 64]
                 + z_out[(size_t)dq * DD + j + 64];
        float xpA = hA + bo_all[j], xpB = hB + bo_all[j + 64];
        float s = xpA + xpB;
        s += __shfl_xor(s, 32); s += __shfl_xor(s, 16); s += __shfl_xor(s, 8);
        s += __shfl_xor(s, 4);  s += __shfl_xor(s, 2);  s += __shfl_xor(s, 1);
        float mu = s * (1.f / 128.f);
        float cA = xpA - mu, cB = xpB - mu;
        float v = cA * cA + cB * cB;
        v += __shfl_xor(v, 32); v += __shfl_xor(v, 16); v += __shfl_xor(v, 8);
        v += __shfl_xor(v, 4);  v += __shfl_xor(v, 2);  v += __shfl_xor(v, 1);
        float r = rsqrtf(v * (1.f / 128.f) + 1e-5f);
        ybuf[wn][j] = cA * r * g_all[j] + b_all[j];
        ybuf[wn][j + 64] = cB * r * g_all[j + 64] + b_all[j + 64];
        xps[wn][j] = xpA;
        xps[wn][j + 64] = xpB;
    }
    __syncthreads();

    const int ng = (tid >> 6) & 3;      // node group of 4 (16 nodes)
    const int ks = tid >> 8;            // K-slice 0..3
    float2 acc[4];

    // ---- FF0 GEMM (K=128, slice=32) ----
#pragma unroll
    for (int i = 0; i < 4; ++i) acc[i] = make_float2(0.f, 0.f);
    gemm24(Wff_all, ks * 32, 8, c2, &ybuf[ng * 4][0], acc);
#pragma unroll
    for (int i = 0; i < 4; ++i) *(float2*)&part[ks][ng * 4 + i][c2] = acc[i];
    __syncthreads();

    // ---- fused: FF0-reduce + residual + LN(layer1) ----
    {
        float vA = part[0][wn][j] + part[1][wn][j] + part[2][wn][j] + part[3][wn][j];
        float vB = part[0][wn][j + 64] + part[1][wn][j + 64]
                 + part[2][wn][j + 64] + part[3][wn][j + 64];
        float hA = vA + bff_all[j] + xps[wn][j];
        float hB = vB + bff_all[j + 64] + xps[wn][j + 64];
        float xpA = hA + bo_all[DD + j], xpB = hB + bo_all[DD + j + 64];
        float s = xpA + xpB;
        s += __shfl_xor(s, 32); s += __shfl_xor(s, 16); s += __shfl_xor(s, 8);
        s += __shfl_xor(s, 4);  s += __shfl_xor(s, 2);  s += __shfl_xor(s, 1);
        float mu = s * (1.f / 128.f);
        float cA = xpA - mu, cB = xpB - mu;
        float v = cA * cA + cB * cB;
        v += __shfl_xor(v, 32); v += __shfl_xor(v, 16); v += __shfl_xor(v, 8);
        v += __shfl_xor(v, 4);  v += __shfl_xor(v, 2);  v += __shfl_xor(v, 1);
        float r = rsqrtf(v * (1.f / 128.f) + 1e-5f);
        ybuf[wn][j] = cA * r * g_all[DD + j] + b_all[DD + j];
        ybuf[wn][j + 64] = cB * r * g_all[DD + j + 64] + b_all[DD + j + 64];
        xps[wn][j] = xpA;
        xps[wn][j + 64] = xpB;
    }
    __syncthreads();

    // ---- FF1 GEMM ----
#pragma unroll
    for (int i = 0; i < 4; ++i) acc[i] = make_float2(0.f, 0.f);
    gemm24(Wff_all + DD * DD, ks * 32, 8, c2, &ybuf[ng * 4][0], acc);
#pragma unroll
    for (int i = 0; i < 4; ++i) *(float2*)&part[ks][ng * 4 + i][c2] = acc[i];
    __syncthreads();

    // ---- fused: FF1-reduce + residual -> h (into ybuf for out-GEMM) ----
    {
        float vA = part[0][wn][j] + part[1][wn][j] + part[2][wn][j] + part[3][wn][j];
        float vB = part[0][wn][j + 64] + part[1][wn][j + 64]
                 + part[2][wn][j + 64] + part[3][wn][j + 64];
        ybuf[wn][j] = vA + bff_all[DD + j] + xps[wn][j];
        ybuf[wn][j + 64] = vB + bff_all[DD + j + 64] + xps[wn][j + 64];
    }
    __syncthreads();

    // ---- out GEMM ----
#pragma unroll
    for (int i = 0; i < 4; ++i) acc[i] = make_float2(0.f, 0.f);
    gemm24(W_out, ks * 32, 8, c2, &ybuf[ng * 4][0], acc);
#pragma unroll
    for (int i = 0; i < 4; ++i) *(float2*)&part[ks][ng * 4 + i][c2] = acc[i];
    __syncthreads();

    // ---- final reduce + b_out + store (coalesced) ----
    {
        float vA = part[0][wn][j] + part[1][wn][j] + part[2][wn][j] + part[3][wn][j];
        float vB = part[0][wn][j + 64] + part[1][wn][j + 64]
                 + part[2][wn][j + 64] + part[3][wn][j + 64];
        out[(size_t)(n0 + wn) * DD + j] = vA + b_out[j];
        out[(size_t)(n0 + wn) * DD + j + 64] = vB + b_out[j + 64];
    }
}

extern "C" void kernel_launch(void* const* d_in, const int* in_sizes, int n_in,
                              void* d_out, int out_size, void* d_ws, size_t ws_size,
                              hipStream_t stream) {
    // inputs: 0 x, 1 edge_index, 2 ptr, 3 dist, 4 W_in, 5 b_in, 6 z_in, 7 z_out,
    // 8 b_spat, 9 Wq, 10 bq, 11 Wk, 12 bk, 13 Wv, 14 bv, 15 Wo, 16 bo,
    // 17 ln1_g, 18 ln1_b, 19 ln2_g, 20 ln2_b, 21 Wff, 22 bff, 23 W_out, 24 b_out
    const float* x = (const float*)d_in[0];
    const int* ei = (const int*)d_in[1];
    const float* W_in = (const float*)d_in[4];
    const float* b_in = (const float*)d_in[5];
    const float* z_in = (const float*)d_in[6];
    const float* z_out = (const float*)d_in[7];
    const float* bo = (const float*)d_in[16];
    const float* ln2_g = (const float*)d_in[19];
    const float* ln2_b = (const float*)d_in[20];
    const float* Wff = (const float*)d_in[21];
    const float* bff = (const float*)d_in[22];
    const float* W_out = (const float*)d_in[23];
    const float* b_out = (const float*)d_in[24];
    float* out = (float*)d_out;

    k_one<<<NN / 16, 1024, 0, stream>>>(x, ei, W_in, b_in, z_in, z_out,
                                        bo, ln2_g, ln2_b, Wff, bff, W_out, b_out, out);
}

// Round 13
// 26.117 us; speedup vs baseline: 1.9302x; 1.4278x over previous
//
#include <hip/hip_runtime.h>

#define NN 4096
#define EE 65536
#define DD 128

// acc[i] += y[ng*8+i] @ W over this thread's K-quarter; one W dword -> 8 FMAs.
__device__ __forceinline__ void gemmq(const float* __restrict__ W, int kstart,
                                      int nk4, int c, const float* __restrict__ y,
                                      int ystr, float acc[8]) {
#pragma unroll 2
    for (int k4 = 0; k4 < nk4; ++k4) {
        int k = kstart + k4 * 4;
        float4 yv[8];
#pragma unroll
        for (int i = 0; i < 8; ++i)
            yv[i] = *(const float4*)&y[i * ystr + k];   // LDS broadcast (uniform addr)
#pragma unroll
        for (int kk = 0; kk < 4; ++kk) {
            float w = W[(size_t)(k + kk) * DD + c];     // L1, 8-way reuse across nodes
#pragma unroll
            for (int i = 0; i < 8; ++i) {
                float e = kk == 0 ? yv[i].x : kk == 1 ? yv[i].y
                        : kk == 2 ? yv[i].z : yv[i].w;
                acc[i] += e * w;
            }
        }
    }
}

// Single kernel: in-block degree scan + fused h0 -> layer0 -> layer1 -> out.
// Attention output is exactly zero (multiplicative -1e6 mask => softmax max is a
// huge positive cross-graph logit => within-graph exp underflows to 0; the zero
// mask then kills the cross-graph cols), so only xp=h+bo and the LN2/FF path survive.
// 256 blocks x 1024 thr; thread = (c=tid&127, ng=(tid>>7)&1 [8 nodes], ks=tid>>8 [K/4]).
__global__ __launch_bounds__(1024) void k_one(
    const float* __restrict__ x, const int* __restrict__ ei,
    const float* __restrict__ W_in, const float* __restrict__ b_in,
    const float* __restrict__ z_in, const float* __restrict__ z_out,
    const float* __restrict__ bo_all, const float* __restrict__ g_all,
    const float* __restrict__ b_all, const float* __restrict__ Wff_all,
    const float* __restrict__ bff_all, const float* __restrict__ W_out,
    const float* __restrict__ b_out, float* __restrict__ out) {
    __shared__ float part[4][16][DD];   // 32KB K-split partials
    __shared__ float hbuf[16][DD];      // 8KB  h / xp
    __shared__ float ybuf[16][DD];      // 8KB  LN output
    __shared__ float xs[16][64];        // 4KB  staged x rows
    __shared__ int cin[16], cout_[16];
    const int tid = threadIdx.x;
    const int n0 = blockIdx.x * 16;
    const int c = tid & 127;
    const int ng = (tid >> 7) & 1;
    const int ks = tid >> 8;            // 0..3

    // ---- stage x rows + zero degree counters ----
    xs[tid >> 6][tid & 63] = x[(size_t)(n0 + (tid >> 6)) * 64 + (tid & 63)];
    if (tid < 16) { cin[tid] = 0; cout_[tid] = 0; }
    __syncthreads();

    float acc[8];

    // ---- h0 GEMM (K=64, quarter=16) ----
#pragma unroll
    for (int i = 0; i < 8; ++i) acc[i] = 0.f;
    gemmq(W_in, ks * 16, 4, c, &xs[ng * 8][0], 64, acc);
#pragma unroll
    for (int i = 0; i < 8; ++i) part[ks][ng * 8 + i][c] = acc[i];

    // ---- degree scan: count this block's 16 nodes over all edges ----
    {
        const int4* s4 = (const int4*)ei;
        const int4* d4 = (const int4*)(ei + EE);
        for (int i = tid; i < EE / 4; i += 1024) {
            int4 s = s4[i];
            if ((unsigned)(s.x - n0) < 16u) atomicAdd(&cout_[s.x - n0], 1);
            if ((unsigned)(s.y - n0) < 16u) atomicAdd(&cout_[s.y - n0], 1);
            if ((unsigned)(s.z - n0) < 16u) atomicAdd(&cout_[s.z - n0], 1);
            if ((unsigned)(s.w - n0) < 16u) atomicAdd(&cout_[s.w - n0], 1);
            int4 d = d4[i];
            if ((unsigned)(d.x - n0) < 16u) atomicAdd(&cin[d.x - n0], 1);
            if ((unsigned)(d.y - n0) < 16u) atomicAdd(&cin[d.y - n0], 1);
            if ((unsigned)(d.z - n0) < 16u) atomicAdd(&cin[d.z - n0], 1);
            if ((unsigned)(d.w - n0) < 16u) atomicAdd(&cin[d.w - n0], 1);
        }
    }
    __syncthreads();

    // ---- h0 reduce + bias + centrality tables ----
#pragma unroll
    for (int p = 0; p < 2; ++p) {
        int idx = tid + p * 1024;
        int n = idx >> 7, cc = idx & 127;
        float v = part[0][n][cc] + part[1][n][cc] + part[2][n][cc] + part[3][n][cc];
        int di = min(cin[n], 63), dq = min(cout_[n], 63);
        hbuf[n][cc] = v + b_in[cc] + z_in[(size_t)di * DD + cc]
                        + z_out[(size_t)dq * DD + cc];
    }
    __syncthreads();

    // ---- 2 layers: xp = h + bo; h = LN(xp)@Wff + bff + xp ----
#pragma unroll
    for (int l = 0; l < 2; ++l) {
        // LN: wave-per-node, lane j handles cols j and j+64
        {
            int n = tid >> 6, j = tid & 63;
            float xpA = hbuf[n][j] + bo_all[l * DD + j];
            float xpB = hbuf[n][j + 64] + bo_all[l * DD + j + 64];
            float s = xpA + xpB;
            s += __shfl_xor(s, 32); s += __shfl_xor(s, 16); s += __shfl_xor(s, 8);
            s += __shfl_xor(s, 4);  s += __shfl_xor(s, 2);  s += __shfl_xor(s, 1);
            float mu = s * (1.f / 128.f);
            float cA = xpA - mu, cB = xpB - mu;
            float v = cA * cA + cB * cB;
            v += __shfl_xor(v, 32); v += __shfl_xor(v, 16); v += __shfl_xor(v, 8);
            v += __shfl_xor(v, 4);  v += __shfl_xor(v, 2);  v += __shfl_xor(v, 1);
            float rstd = rsqrtf(v * (1.f / 128.f) + 1e-5f);
            ybuf[n][j]      = cA * rstd * g_all[l * DD + j] + b_all[l * DD + j];
            ybuf[n][j + 64] = cB * rstd * g_all[l * DD + j + 64] + b_all[l * DD + j + 64];
            hbuf[n][j] = xpA;        // keep xp for residual (same-thread overwrite)
            hbuf[n][j + 64] = xpB;
        }
        __syncthreads();

        // FF GEMM (K=128, quarter=32)
        const float* Wl = Wff_all + l * DD * DD;
#pragma unroll
        for (int i = 0; i < 8; ++i) acc[i] = 0.f;
        gemmq(Wl, ks * 32, 8, c, &ybuf[ng * 8][0], DD, acc);
#pragma unroll
        for (int i = 0; i < 8; ++i) part[ks][ng * 8 + i][c] = acc[i];
        __syncthreads();

        // reduce + bff + residual
#pragma unroll
        for (int p = 0; p < 2; ++p) {
            int idx = tid + p * 1024;
            int n = idx >> 7, cc = idx & 127;
            float v = part[0][n][cc] + part[1][n][cc] + part[2][n][cc] + part[3][n][cc];
            hbuf[n][cc] = v + bff_all[l * DD + cc] + hbuf[n][cc];   // hbuf held xp
        }
        __syncthreads();
    }

    // ---- out = h @ W_out + b_out ----
#pragma unroll
    for (int i = 0; i < 8; ++i) acc[i] = 0.f;
    gemmq(W_out, ks * 32, 8, c, &hbuf[ng * 8][0], DD, acc);
#pragma unroll
    for (int i = 0; i < 8; ++i) part[ks][ng * 8 + i][c] = acc[i];
    __syncthreads();
#pragma unroll
    for (int p = 0; p < 2; ++p) {
        int idx = tid + p * 1024;
        int n = idx >> 7, cc = idx & 127;
        float v = part[0][n][cc] + part[1][n][cc] + part[2][n][cc] + part[3][n][cc];
        out[(size_t)(n0 + n) * DD + cc] = v + b_out[cc];
    }
}

extern "C" void kernel_launch(void* const* d_in, const int* in_sizes, int n_in,
                              void* d_out, int out_size, void* d_ws, size_t ws_size,
                              hipStream_t stream) {
    // inputs: 0 x, 1 edge_index, 2 ptr, 3 dist, 4 W_in, 5 b_in, 6 z_in, 7 z_out,
    // 8 b_spat, 9 Wq, 10 bq, 11 Wk, 12 bk, 13 Wv, 14 bv, 15 Wo, 16 bo,
    // 17 ln1_g, 18 ln1_b, 19 ln2_g, 20 ln2_b, 21 Wff, 22 bff, 23 W_out, 24 b_out
    const float* x = (const float*)d_in[0];
    const int* ei = (const int*)d_in[1];
    const float* W_in = (const float*)d_in[4];
    const float* b_in = (const float*)d_in[5];
    const float* z_in = (const float*)d_in[6];
    const float* z_out = (const float*)d_in[7];
    const float* bo = (const float*)d_in[16];
    const float* ln2_g = (const float*)d_in[19];
    const float* ln2_b = (const float*)d_in[20];
    const float* Wff = (const float*)d_in[21];
    const float* bff = (const float*)d_in[22];
    const float* W_out = (const float*)d_in[23];
    const float* b_out = (const float*)d_in[24];
    float* out = (float*)d_out;

    k_one<<<NN / 16, 1024, 0, stream>>>(x, ei, W_in, b_in, z_in, z_out,
                                        bo, ln2_g, ln2_b, Wff, bff, W_out, b_out, out);
}